// Round 18
// baseline (76.895 us; speedup 1.0000x reference)
//
#include <hip/hip_runtime.h>
#include <stdint.h>

// Sizes fixed by the problem.
#define DM 1024   // D_MODEL
#define NN 2048   // NUM_NEURONS
#define BB 64     // batch (== wavefront size!)

static constexpr float INV2PI = 0.15915494309189535f;

__device__ __forceinline__ uint32_t bf16r(float x) {
  uint32_t b = __float_as_uint(x);
  b += 0x7fffu + ((b >> 16) & 1u);
  return b >> 16;
}

// ---------------- K0: xcombP transpose only (32 blocks) ----------------
// x_real/x_imag [64][1024] -> xcombP [1024 kpair][64 b] float2
__global__ __launch_bounds__(256) void k0_prep(
    const float* __restrict__ xr, const float* __restrict__ xi,
    float* __restrict__ xcombP)
{
  __shared__ float tile[64][65];
  int bid = blockIdx.x;
  int t = threadIdx.x;
  int k0 = bid * 64;
  const float* src = (k0 < 1024) ? xr : xi;
  int koff = k0 & 1023;
  int c = t & 63, rl = t >> 6;
#pragma unroll
  for (int i = 0; i < 16; ++i) {
    int b = rl * 16 + i;
    tile[b][c] = src[b * 1024 + koff + c];  // tile[b][k_local]
  }
  __syncthreads();
  float2* out2 = (float2*)xcombP;  // [1024 kpair][64 b]
  int bl = t & 63, kp = t >> 6;    // kp 0..3
#pragma unroll
  for (int i = 0; i < 8; ++i) {
    int kl = (kp * 8 + i) * 2;
    float2 v = make_float2(tile[bl][kl], tile[bl][kl + 1]);
    out2[(size_t)((k0 + kl) >> 1) * 64 + bl] = v;
  }
}

// ---------------- K1: x_collapsed GEMM (blocks 0-255) + rinv (256-511) -----
// GEMM: xc[b,d] = sum_k xcomb[b,k]*ic_w[d,k] + ic_b[d]; f32 xc*INV2PI ->
// xcq in float4-group layout: [dgroup=d>>2][b] float4.
// rinv blocks: rinv = 1/(1+|W|) elementwise, overlapping the GEMM.
__global__ __launch_bounds__(1024) void k1_collapse(
    const float* __restrict__ xcombP, const float* __restrict__ icw,
    const float* __restrict__ icb, const float* __restrict__ W,
    float* __restrict__ xcq, float* __restrict__ rinv)
{
  __shared__ float part[16][4][64];
  int bid = blockIdx.x;
  int t = threadIdx.x;
  if (bid >= 256) {  // rinv: 256 blocks x 1024 thr x 2 float4
    int j = bid - 256;
    const float4* W4 = (const float4*)W;
    float4* R4 = (float4*)rinv;
    int base = j * 2048 + t;
#pragma unroll
    for (int i = 0; i < 2; ++i) {
      int idx = base + i * 1024;
      float4 w = W4[idx];
      float4 r;
      r.x = 1.0f / (1.0f + fabsf(w.x));
      r.y = 1.0f / (1.0f + fabsf(w.y));
      r.z = 1.0f / (1.0f + fabsf(w.z));
      r.w = 1.0f / (1.0f + fabsf(w.w));
      R4[idx] = r;
    }
    return;
  }
  int d0 = bid * 4;
  int wave = __builtin_amdgcn_readfirstlane((int)(t >> 6));
  int lane = t & 63;
  const float2* P2 = (const float2*)xcombP;
  float acc[4] = {0.f, 0.f, 0.f, 0.f};
  int kbase = wave * 128;
  for (int kk = 0; kk < 128; kk += 4) {
    int k = kbase + kk;
    float2 xa = P2[(size_t)(k >> 1) * 64 + lane];        // k, k+1
    float2 xb = P2[(size_t)((k >> 1) + 1) * 64 + lane];  // k+2, k+3
#pragma unroll
    for (int r = 0; r < 4; ++r) {
      float4 w = *(const float4*)(icw + (size_t)(d0 + r) * 2048 + k);  // s_load
      acc[r] = fmaf(w.x, xa.x, acc[r]);
      acc[r] = fmaf(w.y, xa.y, acc[r]);
      acc[r] = fmaf(w.z, xb.x, acc[r]);
      acc[r] = fmaf(w.w, xb.y, acc[r]);
    }
  }
#pragma unroll
  for (int r = 0; r < 4; ++r) part[wave][r][lane] = acc[r];
  __syncthreads();
  if (t < 128) {
    int pj = t >> 6;  // 0..1 (d-pair within tile)
    int b = t & 63;
    float s0 = 0.f, s1 = 0.f;
#pragma unroll
    for (int w = 0; w < 16; ++w) {
      s0 += part[w][2 * pj][b];
      s1 += part[w][2 * pj + 1][b];
    }
    float x0 = (s0 + icb[d0 + 2 * pj]) * INV2PI;
    float x1 = (s1 + icb[d0 + 2 * pj + 1]) * INV2PI;
    // float4-group layout: group = bid; lane b holds d0..d0+3 contiguously
    ((float2*)xcq)[(size_t)bid * 128 + b * 2 + pj] = make_float2(x0, x1);
  }
}

// ---------------- K2: resonant map-reduce (pipelined multi-n) --------------
// lane = b. Block: d-sixteenth q (64 d) x 32 n; wave owns 4 consecutive n.
// xlds (16 KB q-slice) staged ONCE per block; per-n params (1 KB/wave)
// double-buffered via counted vmcnt (loads never drained to 0 in-loop).
// Grid 1024 = 4 blocks/CU exactly resident (32 waves/CU), zero tail.
// Output: packed bf16 (cos,sin) partials cssP[q][n][b], q = 0..15.
#define K2_STEP(r4, b4, a4, s4, xv)                                       \
  do {                                                                     \
    float rv0 = fmaf((xv).x, (r4).x, fmaf((b4).x, INV2PI, t2));            \
    accc0 = fmaf(__builtin_amdgcn_cosf(rv0), (a4).x, accc0);               \
    accs0 = fmaf(__builtin_amdgcn_sinf(rv0), (s4).x, accs0);               \
    float rv1 = fmaf((xv).y, (r4).y, fmaf((b4).y, INV2PI, t2));            \
    accc1 = fmaf(__builtin_amdgcn_cosf(rv1), (a4).y, accc1);               \
    accs1 = fmaf(__builtin_amdgcn_sinf(rv1), (s4).y, accs1);               \
    float rv2 = fmaf((xv).z, (r4).z, fmaf((b4).z, INV2PI, t2));            \
    accc0 = fmaf(__builtin_amdgcn_cosf(rv2), (a4).z, accc0);               \
    accs0 = fmaf(__builtin_amdgcn_sinf(rv2), (s4).z, accs0);               \
    float rv3 = fmaf((xv).w, (r4).w, fmaf((b4).w, INV2PI, t2));            \
    accc1 = fmaf(__builtin_amdgcn_cosf(rv3), (a4).w, accc1);               \
    accs1 = fmaf(__builtin_amdgcn_sinf(rv3), (s4).w, accs1);               \
  } while (0)

__global__ __launch_bounds__(512) void k2_resonant(
    const float* __restrict__ xcq, const float* __restrict__ rinv,
    const float* __restrict__ Bp, const float* __restrict__ ac,
    const float* __restrict__ as_, const float* __restrict__ tin,
    uint32_t* __restrict__ cssP)
{
  __shared__ __align__(16) float4 xlds[16][64];         // 16 KB: d-sixteenth
  __shared__ __align__(16) float plds[2][8][4][16][4];  // 16 KB: param dbuf
  int wave = __builtin_amdgcn_readfirstlane((int)(threadIdx.x >> 6));
  int lane = threadIdx.x & 63;
  int bid = blockIdx.x;
  int q = bid & 15;                       // d-sixteenth (64 d)
  int nbase = (bid >> 4) * 32 + wave * 4; // 4 consecutive n per wave
  float t2 = tin[lane] * INV2PI;

  // ---- stage xcq sixteenth-slice (linear 16 KB): 16 x 1KB; wave w does 2
  const char* xsrc = (const char*)xcq + (size_t)q * 16384;
  char* xdst = (char*)&xlds[0][0];
#pragma unroll
  for (int r = 0; r < 2; ++r) {
    int j = wave * 2 + r;
    __builtin_amdgcn_global_load_lds(
        (const __attribute__((address_space(1))) void*)(xsrc + j * 1024 + lane * 16),
        (__attribute__((address_space(3))) void*)(xdst + j * 1024), 16, 0, 0);
  }

  // ---- param stage source: lane l -> array (l>>4), elements (l&15)*4;
  // 1 KB per (wave, n) in ONE call.
  int g = lane >> 4;
  const float* ab = (g == 0) ? rinv : (g == 1) ? Bp : (g == 2) ? ac : as_;
  const float* gp0 = ab + (size_t)nbase * 1024 + (size_t)q * 64 + (lane & 15) * 4;

  // prologue: stage n=0 params
  __builtin_amdgcn_global_load_lds(
      (const __attribute__((address_space(1))) void*)gp0,
      (__attribute__((address_space(3))) void*)&plds[0][wave][0][0][0], 16, 0, 0);

  __syncthreads();  // drains all staging (xlds + n0 params)

#pragma unroll
  for (int j = 0; j < 4; ++j) {
    if (j < 3) {  // prefetch params for n = nbase + j + 1
      __builtin_amdgcn_global_load_lds(
          (const __attribute__((address_space(1))) void*)(gp0 + (j + 1) * 1024),
          (__attribute__((address_space(3))) void*)&plds[(j + 1) & 1][wave][0][0][0],
          16, 0, 0);
    }
    // in-order vmcnt retirement: outstanding at this point (oldest first):
    // j=1,2: [load_j, store_{j-1}, load_{j+1}] -> vmcnt(2) retires load_j
    // j=3:   [load_3, store_2]                 -> vmcnt(1) retires load_3
    if (j == 1 || j == 2) {
      asm volatile("s_waitcnt vmcnt(2)" ::: "memory");
    } else if (j == 3) {
      asm volatile("s_waitcnt vmcnt(1)" ::: "memory");
    }

    float accc0 = 0.f, accs0 = 0.f, accc1 = 0.f, accs1 = 0.f;
    const float4* pr = (const float4*)&plds[j & 1][wave][0][0][0];  // [4][16]
#pragma unroll 4
    for (int i = 0; i < 16; ++i) {
      float4 xv = xlds[i][lane];  // ds_read_b128: d = q*64 + 4i .. +3
      float4 r4 = pr[i];
      float4 b4 = pr[16 + i];
      float4 a4 = pr[32 + i];
      float4 s4 = pr[48 + i];
      K2_STEP(r4, b4, a4, s4, xv);
    }
    size_t o = ((size_t)q * 2048 + nbase + j) * 64 + lane;
    cssP[o] = bf16r(accc0 + accc1) | (bf16r(accs0 + accs1) << 16);
  }
}

// ---------------- K2b: sum the 16 d-sixteenth partials, pack bf16 pairs ---
// csB/ssB[npair][b] u32 = bf16(n even) | bf16(n odd)<<16.
__global__ __launch_bounds__(256) void k2b_reduce(
    const uint32_t* __restrict__ cssP,
    uint32_t* __restrict__ csB, uint32_t* __restrict__ ssB)
{
  int i = blockIdx.x * 256 + threadIdx.x;  // 0..65535 (npair, b)
  int np = i >> 6, b = i & 63;
  int n0 = 2 * np;
  float c0 = 0.f, c1 = 0.f, s0 = 0.f, s1 = 0.f;
#pragma unroll
  for (int j = 0; j < 16; ++j) {
    size_t base = ((size_t)j * 2048 + n0) * 64 + b;
    uint32_t u0 = cssP[base];
    uint32_t u1 = cssP[base + 64];
    c0 += __uint_as_float(u0 << 16);
    s0 += __uint_as_float(u0 & 0xffff0000u);
    c1 += __uint_as_float(u1 << 16);
    s1 += __uint_as_float(u1 & 0xffff0000u);
  }
  csB[i] = bf16r(c0) | (bf16r(c1) << 16);
  ssB[i] = bf16r(s0) | (bf16r(s1) << 16);
}

// ---------------- K3: output GEMMs + SiLU (packed src, 16 waves; R9 form) --
__global__ __launch_bounds__(1024) void k3_out(
    const uint32_t* __restrict__ csB, const uint32_t* __restrict__ ssB,
    const float* __restrict__ wr, const float* __restrict__ wi,
    float* __restrict__ out)
{
  __shared__ float part[16][4][65];
  int bid = blockIdx.x;
  int sel = bid >> 8;
  int d0 = (bid & 255) * 4;
  int wave = __builtin_amdgcn_readfirstlane((int)(threadIdx.x >> 6));
  int lane = threadIdx.x & 63;
  const uint32_t* src2 = sel ? ssB : csB;
  const float* wt = sel ? wi : wr;
  float acc[4] = {0.f, 0.f, 0.f, 0.f};
  int n0 = wave * 128;
  for (int i = 0; i < 32; ++i) {  // 4 n per iter
    int n = n0 + i * 4;
    uint32_t xu0 = src2[(size_t)(n >> 1) * 64 + lane];
    uint32_t xu1 = src2[(size_t)((n >> 1) + 1) * 64 + lane];
    float cv0 = __uint_as_float(xu0 << 16);
    float cv1 = __uint_as_float(xu0 & 0xffff0000u);
    float cv2 = __uint_as_float(xu1 << 16);
    float cv3 = __uint_as_float(xu1 & 0xffff0000u);
#pragma unroll
    for (int r = 0; r < 4; ++r) {
      float4 wv = *(const float4*)(wt + (size_t)(d0 + r) * 2048 + n);  // s_load
      acc[r] = fmaf(cv0, wv.x, acc[r]);
      acc[r] = fmaf(cv1, wv.y, acc[r]);
      acc[r] = fmaf(cv2, wv.z, acc[r]);
      acc[r] = fmaf(cv3, wv.w, acc[r]);
    }
  }
#pragma unroll
  for (int r = 0; r < 4; ++r) part[wave][r][lane] = acc[r];
  __syncthreads();
  int t = threadIdx.x;
  if (t < 256) {
    int b = t >> 2, j = t & 3;
    float s = 0.f;
#pragma unroll
    for (int w = 0; w < 16; ++w) s += part[w][j][b];
    float y = s / (1.0f + __expf(-s));  // silu
    out[(size_t)sel * 65536 + (size_t)b * 1024 + d0 + j] = y;
  }
}

extern "C" void kernel_launch(void* const* d_in, const int* in_sizes, int n_in,
                              void* d_out, int out_size, void* d_ws, size_t ws_size,
                              hipStream_t stream) {
  const float* xr  = (const float*)d_in[0];
  const float* xi  = (const float*)d_in[1];
  const float* t   = (const float*)d_in[2];
  const float* icw = (const float*)d_in[3];
  const float* icb = (const float*)d_in[4];
  const float* W   = (const float*)d_in[5];
  const float* Bp  = (const float*)d_in[6];
  const float* ac  = (const float*)d_in[7];
  const float* as_ = (const float*)d_in[8];
  const float* wr  = (const float*)d_in[9];
  const float* wi  = (const float*)d_in[10];
  // sin/cos tables (d_in[11], d_in[12]) replaced by hw v_sin/v_cos (err ~1e-6)

  float* ws = (float*)d_ws;
  float* rinv    = ws;                          // 2M f32
  float* xcombP  = ws + 2097152;                // 131072
  float* xcq     = ws + 2228224;                // 65536 f32 (float4-group layout)
  uint32_t* cssP = (uint32_t*)(ws + 2293760);   // 2097152 u32 (16 x 2048 x 64)
  uint32_t* csB  = (uint32_t*)(ws + 4390912);   // 65536 u32
  uint32_t* ssB  = (uint32_t*)(ws + 4456448);   // 65536 u32
  float* out = (float*)d_out;

  k0_prep<<<dim3(32), dim3(256), 0, stream>>>(xr, xi, xcombP);
  k1_collapse<<<dim3(512), dim3(1024), 0, stream>>>(xcombP, icw, icb, W, xcq, rinv);
  k2_resonant<<<dim3(1024), dim3(512), 0, stream>>>(xcq, rinv, Bp, ac, as_, t, cssP);
  k2b_reduce<<<dim3(256), dim3(256), 0, stream>>>(cssP, csB, ssB);
  k3_out<<<dim3(512), dim3(1024), 0, stream>>>(csB, ssB, wr, wi, out);
}

// Round 19
// 73.228 us; speedup vs baseline: 1.0501x; 1.0501x over previous
//
#include <hip/hip_runtime.h>
#include <stdint.h>

// Sizes fixed by the problem.
#define DM 1024   // D_MODEL
#define NN 2048   // NUM_NEURONS
#define BB 64     // batch (== wavefront size!)

static constexpr float INV2PI = 0.15915494309189535f;

__device__ __forceinline__ uint32_t bf16r(float x) {
  uint32_t b = __float_as_uint(x);
  b += 0x7fffu + ((b >> 16) & 1u);
  return b >> 16;
}

// ---------------- K0: xcombP transpose only (32 blocks) ----------------
// x_real/x_imag [64][1024] -> xcombP [1024 kpair][64 b] float2
__global__ __launch_bounds__(256) void k0_prep(
    const float* __restrict__ xr, const float* __restrict__ xi,
    float* __restrict__ xcombP)
{
  __shared__ float tile[64][65];
  int bid = blockIdx.x;
  int t = threadIdx.x;
  int k0 = bid * 64;
  const float* src = (k0 < 1024) ? xr : xi;
  int koff = k0 & 1023;
  int c = t & 63, rl = t >> 6;
#pragma unroll
  for (int i = 0; i < 16; ++i) {
    int b = rl * 16 + i;
    tile[b][c] = src[b * 1024 + koff + c];  // tile[b][k_local]
  }
  __syncthreads();
  float2* out2 = (float2*)xcombP;  // [1024 kpair][64 b]
  int bl = t & 63, kp = t >> 6;    // kp 0..3
#pragma unroll
  for (int i = 0; i < 8; ++i) {
    int kl = (kp * 8 + i) * 2;
    float2 v = make_float2(tile[bl][kl], tile[bl][kl + 1]);
    out2[(size_t)((k0 + kl) >> 1) * 64 + bl] = v;
  }
}

// ---------------- K1: x_collapsed GEMM (blocks 0-255) + rinv (256-511) -----
// GEMM: xc[b,d] = sum_k xcomb[b,k]*ic_w[d,k] + ic_b[d]; f32 xc*INV2PI ->
// xcq in float4-group layout: [dgroup=d>>2][b] float4 (k2 reads b128, no
// unpack). rinv blocks: rinv = 1/(1+|W|) elementwise, overlapping the GEMM.
__global__ __launch_bounds__(1024) void k1_collapse(
    const float* __restrict__ xcombP, const float* __restrict__ icw,
    const float* __restrict__ icb, const float* __restrict__ W,
    float* __restrict__ xcq, float* __restrict__ rinv)
{
  __shared__ float part[16][4][64];
  int bid = blockIdx.x;
  int t = threadIdx.x;
  if (bid >= 256) {  // rinv: 256 blocks x 1024 thr x 2 float4
    int j = bid - 256;
    const float4* W4 = (const float4*)W;
    float4* R4 = (float4*)rinv;
    int base = j * 2048 + t;
#pragma unroll
    for (int i = 0; i < 2; ++i) {
      int idx = base + i * 1024;
      float4 w = W4[idx];
      float4 r;
      r.x = 1.0f / (1.0f + fabsf(w.x));
      r.y = 1.0f / (1.0f + fabsf(w.y));
      r.z = 1.0f / (1.0f + fabsf(w.z));
      r.w = 1.0f / (1.0f + fabsf(w.w));
      R4[idx] = r;
    }
    return;
  }
  int d0 = bid * 4;
  int wave = __builtin_amdgcn_readfirstlane((int)(t >> 6));
  int lane = t & 63;
  const float2* P2 = (const float2*)xcombP;
  float acc[4] = {0.f, 0.f, 0.f, 0.f};
  int kbase = wave * 128;
  for (int kk = 0; kk < 128; kk += 4) {
    int k = kbase + kk;
    float2 xa = P2[(size_t)(k >> 1) * 64 + lane];        // k, k+1
    float2 xb = P2[(size_t)((k >> 1) + 1) * 64 + lane];  // k+2, k+3
#pragma unroll
    for (int r = 0; r < 4; ++r) {
      float4 w = *(const float4*)(icw + (size_t)(d0 + r) * 2048 + k);  // s_load
      acc[r] = fmaf(w.x, xa.x, acc[r]);
      acc[r] = fmaf(w.y, xa.y, acc[r]);
      acc[r] = fmaf(w.z, xb.x, acc[r]);
      acc[r] = fmaf(w.w, xb.y, acc[r]);
    }
  }
#pragma unroll
  for (int r = 0; r < 4; ++r) part[wave][r][lane] = acc[r];
  __syncthreads();
  if (t < 128) {
    int pj = t >> 6;  // 0..1 (d-pair within tile)
    int b = t & 63;
    float s0 = 0.f, s1 = 0.f;
#pragma unroll
    for (int w = 0; w < 16; ++w) {
      s0 += part[w][2 * pj][b];
      s1 += part[w][2 * pj + 1][b];
    }
    float x0 = (s0 + icb[d0 + 2 * pj]) * INV2PI;
    float x1 = (s1 + icb[d0 + 2 * pj + 1]) * INV2PI;
    // float4-group layout: group = bid; lane b holds d0..d0+3 contiguously
    ((float2*)xcq)[(size_t)bid * 128 + b * 2 + pj] = make_float2(x0, x1);
  }
}

// ---------------- K2: the resonant map-reduce (R14 loop, f32 x, no unpack) -
// lane = b. wave owns (n, d-eighth q). 2048 blocks x 8 waves. LDS = 48 KB.
// ALL staging before ONE barrier; inner loop pure LDS+VALU+trans; x read as
// one ds_read_b128 per 4-d step, zero unpack VALU.
// Output: packed bf16 (cos_sum, sin_sum) partials cssP[q][n][b].
#define K2_STEP(r4, b4, a4, s4, xv)                                       \
  do {                                                                     \
    float rv0 = fmaf((xv).x, (r4).x, fmaf((b4).x, INV2PI, t2));            \
    accc0 = fmaf(__builtin_amdgcn_cosf(rv0), (a4).x, accc0);               \
    accs0 = fmaf(__builtin_amdgcn_sinf(rv0), (s4).x, accs0);               \
    float rv1 = fmaf((xv).y, (r4).y, fmaf((b4).y, INV2PI, t2));            \
    accc1 = fmaf(__builtin_amdgcn_cosf(rv1), (a4).y, accc1);               \
    accs1 = fmaf(__builtin_amdgcn_sinf(rv1), (s4).y, accs1);               \
    float rv2 = fmaf((xv).z, (r4).z, fmaf((b4).z, INV2PI, t2));            \
    accc0 = fmaf(__builtin_amdgcn_cosf(rv2), (a4).z, accc0);               \
    accs0 = fmaf(__builtin_amdgcn_sinf(rv2), (s4).z, accs0);               \
    float rv3 = fmaf((xv).w, (r4).w, fmaf((b4).w, INV2PI, t2));            \
    accc1 = fmaf(__builtin_amdgcn_cosf(rv3), (a4).w, accc1);               \
    accs1 = fmaf(__builtin_amdgcn_sinf(rv3), (s4).w, accs1);               \
  } while (0)

__global__ __launch_bounds__(512) void k2_resonant(
    const float* __restrict__ xcq, const float* __restrict__ rinv,
    const float* __restrict__ Bp, const float* __restrict__ ac,
    const float* __restrict__ as_, const float* __restrict__ tin,
    uint32_t* __restrict__ cssP)
{
  __shared__ __align__(16) float4 xlds[32][64];      // 32 KB: d-eighth of xcq
  __shared__ __align__(16) float plds[2][8][4][64];  // 16 KB: params, 2 chunks
  int wave = __builtin_amdgcn_readfirstlane((int)(threadIdx.x >> 6));
  int lane = threadIdx.x & 63;
  int bid = blockIdx.x;
  int q = bid & 7;                 // d-eighth
  int n = (bid >> 3) * 8 + wave;   // neuron
  float t2 = tin[lane] * INV2PI;

  // ---- stage xcq eighth-slice (linear 32 KB): 32 x 1KB calls; wave w does 4
  const char* xsrc = (const char*)xcq + (size_t)q * 32768;
  char* xdst = (char*)&xlds[0][0];
#pragma unroll
  for (int r = 0; r < 4; ++r) {
    int j = wave * 4 + r;
    __builtin_amdgcn_global_load_lds(
        (const __attribute__((address_space(1))) void*)(xsrc + j * 1024 + lane * 16),
        (__attribute__((address_space(3))) void*)(xdst + j * 1024), 16, 0, 0);
  }

  // ---- stage BOTH param chunks for this wave: lane l -> array (l>>4),
  // elements (l&15)*4
  int g = lane >> 4;
  const float* ab = (g == 0) ? rinv : (g == 1) ? Bp : (g == 2) ? ac : as_;
  const float* gp = ab + (size_t)n * 1024 + (size_t)q * 128 + (lane & 15) * 4;
#pragma unroll
  for (int c = 0; c < 2; ++c) {
    __builtin_amdgcn_global_load_lds(
        (const __attribute__((address_space(1))) void*)(gp + c * 64),
        (__attribute__((address_space(3))) void*)&plds[c][wave][0][0], 16, 0, 0);
  }

  __syncthreads();  // drains vmcnt: all LDS staging complete

  float accc0 = 0.f, accs0 = 0.f, accc1 = 0.f, accs1 = 0.f;

#pragma unroll
  for (int c = 0; c < 2; ++c) {
    const float4* pr = (const float4*)&plds[c][wave][0][0];  // [4][16]
#pragma unroll 4
    for (int i = 0; i < 16; ++i) {
      int ga = c * 16 + i;
      float4 xv = xlds[ga][lane];  // ds_read_b128: d = 4*ga .. 4*ga+3
      float4 r4 = pr[i];
      float4 b4 = pr[16 + i];
      float4 a4 = pr[32 + i];
      float4 s4 = pr[48 + i];
      K2_STEP(r4, b4, a4, s4, xv);
    }
  }

  size_t o = ((size_t)q * 2048 + n) * 64 + lane;
  cssP[o] = bf16r(accc0 + accc1) | (bf16r(accs0 + accs1) << 16);
}

// ---------------- K2b: sum the 8 d-eighth partials, pack to bf16 pairs ----
// csB/ssB[npair][b] u32 = bf16(n even) | bf16(n odd)<<16.
__global__ __launch_bounds__(256) void k2b_reduce(
    const uint32_t* __restrict__ cssP,
    uint32_t* __restrict__ csB, uint32_t* __restrict__ ssB)
{
  int i = blockIdx.x * 256 + threadIdx.x;  // 0..65535 (npair, b)
  int np = i >> 6, b = i & 63;
  int n0 = 2 * np;
  float c0 = 0.f, c1 = 0.f, s0 = 0.f, s1 = 0.f;
#pragma unroll
  for (int j = 0; j < 8; ++j) {
    size_t base = ((size_t)j * 2048 + n0) * 64 + b;
    uint32_t u0 = cssP[base];
    uint32_t u1 = cssP[base + 64];
    c0 += __uint_as_float(u0 << 16);
    s0 += __uint_as_float(u0 & 0xffff0000u);
    c1 += __uint_as_float(u1 << 16);
    s1 += __uint_as_float(u1 & 0xffff0000u);
  }
  csB[i] = bf16r(c0) | (bf16r(c1) << 16);
  ssB[i] = bf16r(s0) | (bf16r(s1) << 16);
}

// ---------------- K3: output GEMMs + SiLU (packed src, 16 waves; R9 form) --
__global__ __launch_bounds__(1024) void k3_out(
    const uint32_t* __restrict__ csB, const uint32_t* __restrict__ ssB,
    const float* __restrict__ wr, const float* __restrict__ wi,
    float* __restrict__ out)
{
  __shared__ float part[16][4][65];
  int bid = blockIdx.x;
  int sel = bid >> 8;
  int d0 = (bid & 255) * 4;
  int wave = __builtin_amdgcn_readfirstlane((int)(threadIdx.x >> 6));
  int lane = threadIdx.x & 63;
  const uint32_t* src2 = sel ? ssB : csB;
  const float* wt = sel ? wi : wr;
  float acc[4] = {0.f, 0.f, 0.f, 0.f};
  int n0 = wave * 128;
  for (int i = 0; i < 32; ++i) {  // 4 n per iter
    int n = n0 + i * 4;
    uint32_t xu0 = src2[(size_t)(n >> 1) * 64 + lane];
    uint32_t xu1 = src2[(size_t)((n >> 1) + 1) * 64 + lane];
    float cv0 = __uint_as_float(xu0 << 16);
    float cv1 = __uint_as_float(xu0 & 0xffff0000u);
    float cv2 = __uint_as_float(xu1 << 16);
    float cv3 = __uint_as_float(xu1 & 0xffff0000u);
#pragma unroll
    for (int r = 0; r < 4; ++r) {
      float4 wv = *(const float4*)(wt + (size_t)(d0 + r) * 2048 + n);  // s_load
      acc[r] = fmaf(cv0, wv.x, acc[r]);
      acc[r] = fmaf(cv1, wv.y, acc[r]);
      acc[r] = fmaf(cv2, wv.z, acc[r]);
      acc[r] = fmaf(cv3, wv.w, acc[r]);
    }
  }
#pragma unroll
  for (int r = 0; r < 4; ++r) part[wave][r][lane] = acc[r];
  __syncthreads();
  int t = threadIdx.x;
  if (t < 256) {
    int b = t >> 2, j = t & 3;
    float s = 0.f;
#pragma unroll
    for (int w = 0; w < 16; ++w) s += part[w][j][b];
    float y = s / (1.0f + __expf(-s));  // silu
    out[(size_t)sel * 65536 + (size_t)b * 1024 + d0 + j] = y;
  }
}

extern "C" void kernel_launch(void* const* d_in, const int* in_sizes, int n_in,
                              void* d_out, int out_size, void* d_ws, size_t ws_size,
                              hipStream_t stream) {
  const float* xr  = (const float*)d_in[0];
  const float* xi  = (const float*)d_in[1];
  const float* t   = (const float*)d_in[2];
  const float* icw = (const float*)d_in[3];
  const float* icb = (const float*)d_in[4];
  const float* W   = (const float*)d_in[5];
  const float* Bp  = (const float*)d_in[6];
  const float* ac  = (const float*)d_in[7];
  const float* as_ = (const float*)d_in[8];
  const float* wr  = (const float*)d_in[9];
  const float* wi  = (const float*)d_in[10];
  // sin/cos tables (d_in[11], d_in[12]) replaced by hw v_sin/v_cos (err ~1e-6)

  float* ws = (float*)d_ws;
  float* rinv    = ws;                          // 2M f32
  float* xcombP  = ws + 2097152;                // 131072
  float* xcq     = ws + 2228224;                // 65536 f32 (float4-group layout)
  uint32_t* cssP = (uint32_t*)(ws + 2293760);   // 1048576 u32 (8 x 2048 x 64)
  uint32_t* csB  = (uint32_t*)(ws + 3342336);   // 65536 u32
  uint32_t* ssB  = (uint32_t*)(ws + 3407872);   // 65536 u32
  float* out = (float*)d_out;

  k0_prep<<<dim3(32), dim3(256), 0, stream>>>(xr, xi, xcombP);
  k1_collapse<<<dim3(512), dim3(1024), 0, stream>>>(xcombP, icw, icb, W, xcq, rinv);
  k2_resonant<<<dim3(2048), dim3(512), 0, stream>>>(xcq, rinv, Bp, ac, as_, t, cssP);
  k2b_reduce<<<dim3(256), dim3(256), 0, stream>>>(cssP, csB, ssB);
  k3_out<<<dim3(512), dim3(1024), 0, stream>>>(csB, ssB, wr, wi, out);
}